// Round 10
// baseline (409.938 us; speedup 1.0000x reference)
//
#include <hip/hip_runtime.h>

#define N_BATCH 8
#define I_DIM   32768
#define T_DIM   300
#define O1      410
#define O1P     416               // padded to 104 float4
#define O1Q     104               // float4s per row
#define O2      10
#define KLEN    100
#define NCH_I   16                // i-chunks (2048 rows, 3.4 MB w1t slice)
#define NWORD   (I_DIM / 32)      // 1024 bitmask words per (n,t)
#define CHCAP   128               // max actives per i-chunk
#define NT      (N_BATCH * T_DIM) // 2400
#define GRP     4                 // nt per gather block
#define NTG     (NT / GRP)        // 600
#define PSTRIDE 308               // LDS row stride for psp buffers (16B-aligned)

typedef float nfloat4 __attribute__((ext_vector_type(4)));

__device__ __forceinline__ float4 nt_load4(const float4* p) {
    nfloat4 v = __builtin_nontemporal_load(reinterpret_cast<const nfloat4*>(p));
    return make_float4(v.x, v.y, v.z, v.w);
}
__device__ __forceinline__ void nt_store4(float4* p, float4 v) {
    nfloat4 w = {v.x, v.y, v.z, v.w};
    __builtin_nontemporal_store(w, reinterpret_cast<nfloat4*>(p));
}

// ---- fused prep: blocks [0,8192) build x-bitmask, [8192,11776) transpose w1
__global__ __launch_bounds__(256) void prep_k(const float* __restrict__ x,
                                              const float* __restrict__ w1,
                                              unsigned int* __restrict__ xb,
                                              float* __restrict__ w1t) {
    __shared__ __attribute__((aligned(16))) char smem[39616];
    int b   = blockIdx.x;
    int tid = threadIdx.x;
    if (b < NWORD * N_BATCH) {
        float4*       tile4 = (float4*)smem;
        unsigned int* wbuf  = (unsigned int*)(smem + 38400);
        int w = b & (NWORD - 1);
        int n = b >> 10;
        const float4* src = (const float4*)(x + ((size_t)(n * I_DIM + w * 32)) * T_DIM);
        for (int q = tid; q < 32 * 75; q += 256) tile4[q] = nt_load4(&src[q]);
        __syncthreads();
        const float* tile = (const float*)tile4;
        int wv  = tid >> 6;
        int l   = tid & 63;
        int row = l & 31;
        int th  = l >> 5;
        for (int tp = wv; tp < 150; tp += 4) {
            int t = 2 * tp + th;
            float v = tile[row * 300 + t];
            unsigned long long m = __ballot(v != 0.0f);
            if (l == 0) {
                wbuf[2 * tp]     = (unsigned int)m;
                wbuf[2 * tp + 1] = (unsigned int)(m >> 32);
            }
        }
        __syncthreads();
        if (tid < 75) {
            uint4* dst = (uint4*)(xb + ((size_t)n * NWORD + w) * T_DIM);
            dst[tid] = *(const uint4*)(smem + 38400 + tid * 16);
        }
    } else {
        float (*tile)[65] = reinterpret_cast<float(*)[65]>(smem);
        int bb = b - NWORD * N_BATCH;
        int i0 = (bb & 511) * 64;
        int o0 = (bb >> 9) * 64;
        int tx = tid & 63;
        int ty = tid >> 6;
#pragma unroll
        for (int r = 0; r < 64; r += 4) {
            int o = o0 + r + ty;
            tile[r + ty][tx] = (o < O1)
                ? __builtin_nontemporal_load(&w1[(size_t)o * I_DIM + i0 + tx]) : 0.0f;
        }
        __syncthreads();
#pragma unroll
        for (int r = 0; r < 64; r += 4) {
            int i = i0 + r + ty;
            int o = o0 + tx;
            if (o < O1P) w1t[(size_t)i * O1P + o] = (o < O1) ? tile[tx][r + ty] : 0.0f;
        }
    }
}

__device__ __forceinline__ void add4(float4& a, const float4 b) {
    a.x += b.x; a.y += b.y; a.z += b.z; a.w += b.w;
}

// ------ chunk-pinned sparse gather with in-block bitmask expansion ----------
__global__ __launch_bounds__(512) void gather_partial_k(
        const float4* __restrict__ w1t4, const unsigned int* __restrict__ xb,
        float4* __restrict__ partial4) {
    int b     = blockIdx.x;
    int phase = b / (NTG * 8);
    int rem   = b - phase * (NTG * 8);
    int ntg   = rem >> 3;
    int k     = rem & 7;
    int chunk = phase * 8 + k;
    int nt0   = ntg * GRP;
    int tid   = threadIdx.x;
    int wv    = tid >> 6;
    int l     = tid & 63;

    __shared__ int s_idx[GRP][CHCAP];
    __shared__ int s_cnt[GRP];

    if ((wv & 1) == 0) {
        int g  = wv >> 1;
        int nt = nt0 + g;
        int n  = nt / T_DIM, t = nt - n * T_DIM;
        unsigned int word = xb[((size_t)n * NWORD + chunk * 64 + l) * T_DIM + t];
        int c   = __popc(word);
        int pfx = c;
#pragma unroll
        for (int d = 1; d < 64; d <<= 1) {
            int v = __shfl_up(pfx, d);
            if (l >= d) pfx += v;
        }
        pfx -= c;
        int base = chunk * 2048 + l * 32;
        while (word) {
            int bit = __ffs(word) - 1;
            if (pfx < CHCAP) s_idx[g][pfx] = base + bit;
            pfx++;
            word &= word - 1;
        }
        if (l == 63) s_cnt[g] = (pfx < CHCAP) ? pfx : CHCAP;
    }
    __syncthreads();

    int g  = tid >> 7;
    int oq = tid & 127;
    if (oq < O1Q) {
        const float4* wb = w1t4 + oq;
        int c = s_cnt[g];
        float4 z4 = make_float4(0.f, 0.f, 0.f, 0.f);
        float4 a0 = z4, a1 = z4, a2 = z4, a3 = z4;
        int j = 0;
        for (; j + 4 <= c; j += 4) {
            int4 idx4 = *reinterpret_cast<const int4*>(&s_idx[g][j]);
            add4(a0, wb[(size_t)idx4.x * O1Q]);
            add4(a1, wb[(size_t)idx4.y * O1Q]);
            add4(a2, wb[(size_t)idx4.z * O1Q]);
            add4(a3, wb[(size_t)idx4.w * O1Q]);
        }
        for (; j < c; j++) add4(a0, wb[(size_t)s_idx[g][j] * O1Q]);
        add4(a0, a1); add4(a2, a3); add4(a0, a2);
        nt_store4(&partial4[((size_t)(nt0 + g) * NCH_I + chunk) * O1Q + oq], a0);
    }
}

// ---- linear reduce: up1[n][t][o] = sum_c partial[nt][c][o], both coalesced -
__global__ void reduce_k(const float* __restrict__ partial, float* __restrict__ up1) {
    int id = blockIdx.x * 256 + threadIdx.x;
    if (id >= NT * O1P) return;
    int nt = id / O1P;
    int o  = id - nt * O1P;
    const float* p = partial + (size_t)nt * NCH_I * O1P + o;
    float s = 0.0f;
#pragma unroll
    for (int c = 0; c < NCH_I; c++) s += __builtin_nontemporal_load(p + c * O1P);
    up1[id] = s;   // up1[n][t][o] == linear id: fully coalesced
}

// ---- fused causal FIR (100-tap) + threshold/refractory scan (layer 1) ------
// input up[(n*T + t)*OP + o] (t-major, L2-resident); output s[n][o][t] rows.
__global__ __launch_bounds__(256) void psp_spike_k(const float* __restrict__ up,
                                                   float* __restrict__ s,
                                                   int OP, int O) {
    __shared__ float zrow[16 * PSTRIDE];
    __shared__ float urow[16 * PSTRIDE];
    __shared__ float kern[104];
    int o0  = blockIdx.x * 16;
    int n   = blockIdx.y;
    int tid = threadIdx.x;

    if (tid < 104) {
        float a = (float)tid / 10.0f;
        kern[tid] = (tid < KLEN) ? a * expf(1.0f - a) : 0.0f;
    }
    for (int idx = tid; idx < 16 * T_DIM; idx += 256) {
        int t = idx >> 4, o = idx & 15;
        zrow[o * PSTRIDE + t] = up[((size_t)(n * T_DIM + t)) * OP + o0 + o];
    }
    __syncthreads();
    for (int task = tid; task < 16 * 75; task += 256) {
        int o  = task & 15;
        int t0 = (task >> 4) * 4;
        const float* zr = &zrow[o * PSTRIDE];
        float v0 = zr[t0], v1 = zr[t0 + 1], v2 = zr[t0 + 2], v3 = zr[t0 + 3];
        float a0 = 0.f, a1 = 0.f, a2 = 0.f, a3 = 0.f;
        for (int m = 0; m < KLEN; m++) {
            float km = kern[m];
            a0 += km * v0; a1 += km * v1; a2 += km * v2; a3 += km * v3;
            v3 = v2; v2 = v1; v1 = v0;
            int j = t0 - m - 1;
            v0 = (j >= 0) ? zr[j] : 0.0f;
        }
        *reinterpret_cast<float4*>(&urow[o * PSTRIDE + t0]) = make_float4(a0, a1, a2, a3);
    }
    __syncthreads();
    if (tid < 16) {
        const float A = 0.36787944117144233f;   // exp(-1)
        const float K = -54.365636569180904f;   // -2*10*e
        float p = 0.0f, y = 0.0f;
        float* ur = &urow[tid * PSTRIDE];
        float* sr = &zrow[tid * PSTRIDE];
        for (int t0 = 0; t0 < 296; t0 += 8) {
            float4 ua = *(const float4*)&ur[t0];
            float4 ub = *(const float4*)&ur[t0 + 4];
            float uv[8] = {ua.x, ua.y, ua.z, ua.w, ub.x, ub.y, ub.z, ub.w};
            float sp[8];
#pragma unroll
            for (int q = 0; q < 8; q++) {
                y = A * (y + K * p);
                float v = (uv[q] + y >= 10.0f) ? 1.0f : 0.0f;
                p = A * p + v;
                sp[q] = v;
            }
            *(float4*)&sr[t0]     = make_float4(sp[0], sp[1], sp[2], sp[3]);
            *(float4*)&sr[t0 + 4] = make_float4(sp[4], sp[5], sp[6], sp[7]);
        }
        {
            float4 ua = *(const float4*)&ur[296];
            float uv[4] = {ua.x, ua.y, ua.z, ua.w};
            float sp[4];
#pragma unroll
            for (int q = 0; q < 4; q++) {
                y = A * (y + K * p);
                float v = (uv[q] + y >= 10.0f) ? 1.0f : 0.0f;
                p = A * p + v;
                sp[q] = v;
            }
            *(float4*)&sr[296] = make_float4(sp[0], sp[1], sp[2], sp[3]);
        }
    }
    __syncthreads();
    for (int task = tid; task < 16 * 75; task += 256) {
        int o = task & 15, q = task >> 4;
        int oo = o0 + o;
        if (oo < O) {
            float4 v = *(const float4*)&zrow[o * PSTRIDE + q * 4];
            *reinterpret_cast<float4*>(&s[((size_t)n * O + oo) * T_DIM + q * 4]) = v;
        }
    }
}

// ---- fused layer 2: GEMM (410->10) straight into LDS + FIR + scan ----------
// grid: N_BATCH blocks of 256. gemm acc order identical to R9 gemm2_k.
__global__ __launch_bounds__(256) void gemm2_psp_k(const float* __restrict__ s1,
                                                   const float* __restrict__ w2,
                                                   float* __restrict__ out) {
    __shared__ float w2s[O2 * O1];
    __shared__ float zrow[16 * PSTRIDE];
    __shared__ float urow[16 * PSTRIDE];
    __shared__ float kern[104];
    int n   = blockIdx.x;
    int tid = threadIdx.x;

    for (int q = tid; q < O2 * O1; q += 256) w2s[q] = w2[q];
    if (tid < 104) {
        float a = (float)tid / 10.0f;
        kern[tid] = (tid < KLEN) ? a * expf(1.0f - a) : 0.0f;
    }
    __syncthreads();
    for (int t = tid; t < T_DIM; t += 256) {
        float acc[O2];
#pragma unroll
        for (int k = 0; k < O2; k++) acc[k] = 0.0f;
        const float* sp = s1 + (size_t)n * O1 * T_DIM + t;
#pragma unroll 8
        for (int o = 0; o < O1; o++) {
            float v = sp[(size_t)o * T_DIM];
#pragma unroll
            for (int k = 0; k < O2; k++) acc[k] += w2s[k * O1 + o] * v;
        }
#pragma unroll
        for (int k = 0; k < O2; k++) zrow[k * PSTRIDE + t] = acc[k];
    }
    __syncthreads();
    for (int task = tid; task < 16 * 75; task += 256) {
        int o = task & 15;
        if (o >= O2) continue;
        int t0 = (task >> 4) * 4;
        const float* zr = &zrow[o * PSTRIDE];
        float v0 = zr[t0], v1 = zr[t0 + 1], v2 = zr[t0 + 2], v3 = zr[t0 + 3];
        float a0 = 0.f, a1 = 0.f, a2 = 0.f, a3 = 0.f;
        for (int m = 0; m < KLEN; m++) {
            float km = kern[m];
            a0 += km * v0; a1 += km * v1; a2 += km * v2; a3 += km * v3;
            v3 = v2; v2 = v1; v1 = v0;
            int j = t0 - m - 1;
            v0 = (j >= 0) ? zr[j] : 0.0f;
        }
        *reinterpret_cast<float4*>(&urow[o * PSTRIDE + t0]) = make_float4(a0, a1, a2, a3);
    }
    __syncthreads();
    if (tid < O2) {
        const float A = 0.36787944117144233f;   // exp(-1)
        const float K = -54.365636569180904f;   // -2*10*e
        float p = 0.0f, y = 0.0f;
        float* ur = &urow[tid * PSTRIDE];
        float* sr = &zrow[tid * PSTRIDE];
        for (int t0 = 0; t0 < 296; t0 += 8) {
            float4 ua = *(const float4*)&ur[t0];
            float4 ub = *(const float4*)&ur[t0 + 4];
            float uv[8] = {ua.x, ua.y, ua.z, ua.w, ub.x, ub.y, ub.z, ub.w};
            float sp[8];
#pragma unroll
            for (int q = 0; q < 8; q++) {
                y = A * (y + K * p);
                float v = (uv[q] + y >= 10.0f) ? 1.0f : 0.0f;
                p = A * p + v;
                sp[q] = v;
            }
            *(float4*)&sr[t0]     = make_float4(sp[0], sp[1], sp[2], sp[3]);
            *(float4*)&sr[t0 + 4] = make_float4(sp[4], sp[5], sp[6], sp[7]);
        }
        {
            float4 ua = *(const float4*)&ur[296];
            float uv[4] = {ua.x, ua.y, ua.z, ua.w};
            float sp[4];
#pragma unroll
            for (int q = 0; q < 4; q++) {
                y = A * (y + K * p);
                float v = (uv[q] + y >= 10.0f) ? 1.0f : 0.0f;
                p = A * p + v;
                sp[q] = v;
            }
            *(float4*)&sr[296] = make_float4(sp[0], sp[1], sp[2], sp[3]);
        }
    }
    __syncthreads();
    for (int task = tid; task < O2 * 75; task += 256) {
        int o = task / 75, q = task - o * 75;
        float4 v = *(const float4*)&zrow[o * PSTRIDE + q * 4];
        *reinterpret_cast<float4*>(&out[((size_t)n * O2 + o) * T_DIM + q * 4]) = v;
    }
}

extern "C" void kernel_launch(void* const* d_in, const int* in_sizes, int n_in,
                              void* d_out, int out_size, void* d_ws, size_t ws_size,
                              hipStream_t stream) {
    const float* x  = (const float*)d_in[0];
    const float* w1 = (const float*)d_in[1];
    const float* w2 = (const float*)d_in[2];
    float* out = (float*)d_out;

    char* ws = (char*)d_ws;
    float*        w1t     = (float*)ws;        ws += (size_t)I_DIM * O1P * 4;             // 54.5 MB
    unsigned int* xb      = (unsigned int*)ws; ws += (size_t)N_BATCH * NWORD * T_DIM * 4; // 9.8 MB
    float*        partial = (float*)ws;        ws += (size_t)NT * NCH_I * O1P * 4;        // 63.9 MB
    float*        up1     = (float*)ws;        ws += (size_t)NT * O1P * 4;                // 4.0 MB
    float*        s1      = (float*)ws;                                                   // 3.9 MB

    prep_k<<<NWORD * N_BATCH + 512 * 7, 256, 0, stream>>>(x, w1, xb, w1t);
    gather_partial_k<<<2 * NTG * 8, 512, 0, stream>>>((const float4*)w1t, xb,
                                                      (float4*)partial);
    reduce_k<<<(NT * O1P + 255) / 256, 256, 0, stream>>>(partial, up1);
    psp_spike_k<<<dim3((O1 + 15) / 16, N_BATCH), 256, 0, stream>>>(up1, s1, O1P, O1);
    gemm2_psp_k<<<N_BATCH, 256, 0, stream>>>(s1, w2, out);
}

// Round 12
// 340.564 us; speedup vs baseline: 1.2037x; 1.2037x over previous
//
#include <hip/hip_runtime.h>

#define N_BATCH 8
#define I_DIM   32768
#define T_DIM   300
#define O1      410
#define O1P     416               // padded to 104 float4
#define O1Q     104               // float4s per row
#define O2      10
#define KLEN    100
#define NCH_I   16                // i-chunks (2048 rows, 3.4 MB w1t slice)
#define NWORD   (I_DIM / 32)      // 1024 bitmask words per (n,t)
#define CHCAP   128               // max actives per i-chunk
#define NT      (N_BATCH * T_DIM) // 2400
#define GRP     8                 // nt per gather block; one wave expands+gathers each
#define NTG     (NT / GRP)        // 300
#define PSTRIDE 308               // LDS row stride for psp buffers (16B-aligned)
#define NBM     (NWORD * N_BATCH) // 8192 bitmask blocks

typedef float nfloat4 __attribute__((ext_vector_type(4)));

__device__ __forceinline__ float4 nt_load4(const float4* p) {
    nfloat4 v = __builtin_nontemporal_load(reinterpret_cast<const nfloat4*>(p));
    return make_float4(v.x, v.y, v.z, v.w);
}
__device__ __forceinline__ void nt_store4(float4* p, float4 v) {
    nfloat4 w = {v.x, v.y, v.z, v.w};
    __builtin_nontemporal_store(w, reinterpret_cast<nfloat4*>(p));
}

// ---- fused prep, low-LDS (<=20.6KB both roles -> 7 blocks/CU) --------------
// blocks [0, 8192): x -> bitmask, 16-row tile, two passes per 32-row word.
// blocks [8192, 11776): w1 transpose (410,32768) -> (32768,416) padded.
__global__ __launch_bounds__(256) void prep_k(const float* __restrict__ x,
                                              const float* __restrict__ w1,
                                              unsigned int* __restrict__ xb,
                                              float* __restrict__ w1t) {
    __shared__ __attribute__((aligned(16))) char smem[21104];  // 16*300*4 + 304*4 or 64*65*4
    int b   = blockIdx.x;
    int tid = threadIdx.x;
    if (b < NBM) {
        float*        tile = (float*)smem;                    // 16 x 300
        unsigned int* wbuf = (unsigned int*)(smem + 19200);   // 300 u32 (+pad)
        int w = b & (NWORD - 1);
        int n = b >> 10;
        int wv = tid >> 6;
        int l  = tid & 63;
        int row = l & 15;          // 16 rows per pass
        int th  = l >> 4;          // 4 t-slots per ballot
#pragma unroll
        for (int pass = 0; pass < 2; pass++) {
            const float4* src = (const float4*)(x +
                ((size_t)(n * I_DIM + w * 32 + pass * 16)) * T_DIM);
            float4* tile4 = (float4*)tile;
            for (int q = tid; q < 16 * 75; q += 256) tile4[q] = nt_load4(&src[q]);
            __syncthreads();
            for (int tq = wv; tq < 75; tq += 4) {
                int t = tq * 4 + th;
                float v = tile[row * 300 + t];
                unsigned long long m = __ballot(v != 0.0f);
                if ((l & 15) == 0) {
                    unsigned int half = (unsigned int)((m >> (th * 16)) & 0xFFFFULL);
                    if (pass == 0) wbuf[t] = half;
                    else           wbuf[t] |= half << 16;
                }
            }
            __syncthreads();
        }
        if (tid < 75) {
            uint4* dst = (uint4*)(xb + ((size_t)n * NWORD + w) * T_DIM);
            dst[tid] = ((const uint4*)wbuf)[tid];
        }
    } else {
        float (*tile)[65] = reinterpret_cast<float(*)[65]>(smem);
        int bb = b - NBM;
        int i0 = (bb & 511) * 64;
        int o0 = (bb >> 9) * 64;
        int tx = tid & 63;
        int ty = tid >> 6;
#pragma unroll
        for (int r = 0; r < 64; r += 4) {
            int o = o0 + r + ty;
            tile[r + ty][tx] = (o < O1)
                ? __builtin_nontemporal_load(&w1[(size_t)o * I_DIM + i0 + tx]) : 0.0f;
        }
        __syncthreads();
#pragma unroll
        for (int r = 0; r < 64; r += 4) {
            int i = i0 + r + ty;
            int o = o0 + tx;
            if (o < O1P) w1t[(size_t)i * O1P + o] = (o < O1) ? tile[tx][r + ty] : 0.0f;
        }
    }
}

__device__ __forceinline__ void add4(float4& a, const float4 b) {
    a.x += b.x; a.y += b.y; a.z += b.z; a.w += b.w;
}

// ------ chunk-pinned sparse gather: 512 threads, 8 nt per block -------------
// grid 2*NTG*8; b -> (phase, ntg, k), chunk = phase*8+k; b%8 pins chunk->XCD.
// Wave wv expands AND gathers nt0+wv: 64 lanes sweep o-columns l and l+64.
// Per-(nt,chunk,o) accumulation grouping identical to R6 (bitwise-same sums).
__global__ __launch_bounds__(512) void gather_partial_k(
        const float4* __restrict__ w1t4, const unsigned int* __restrict__ xb,
        float4* __restrict__ partial4) {
    int b     = blockIdx.x;
    int phase = b / (NTG * 8);
    int rem   = b - phase * (NTG * 8);
    int ntg   = rem >> 3;
    int k     = rem & 7;
    int chunk = phase * 8 + k;
    int nt0   = ntg * GRP;
    int tid   = threadIdx.x;
    int wv    = tid >> 6;     // 0..7: wave owns nt0+wv
    int l     = tid & 63;

    __shared__ int s_idx[GRP][CHCAP];
    __shared__ int s_cnt[GRP];

    {   // expansion: all 8 waves busy, ascending-i order
        int nt = nt0 + wv;
        int n  = nt / T_DIM, t = nt - n * T_DIM;
        unsigned int word = xb[((size_t)n * NWORD + chunk * 64 + l) * T_DIM + t];
        int c   = __popc(word);
        int pfx = c;
#pragma unroll
        for (int d = 1; d < 64; d <<= 1) {
            int v = __shfl_up(pfx, d);
            if (l >= d) pfx += v;
        }
        pfx -= c;
        int base = chunk * 2048 + l * 32;
        while (word) {
            int bit = __ffs(word) - 1;
            if (pfx < CHCAP) s_idx[wv][pfx] = base + bit;
            pfx++;
            word &= word - 1;
        }
        if (l == 63) s_cnt[wv] = (pfx < CHCAP) ? pfx : CHCAP;
    }
    __syncthreads();

    {   // gather: wave wv sweeps columns l (all lanes) and l+64 (lanes < 40)
        int c = s_cnt[wv];
        bool two = (l < O1Q - 64);          // l < 40
        const float4* wb1 = w1t4 + l;
        const float4* wb2 = w1t4 + 64 + l;
        float4 z4 = make_float4(0.f, 0.f, 0.f, 0.f);
        float4 a0 = z4, a1 = z4, a2 = z4, a3 = z4;
        float4 b0 = z4, b1 = z4, b2 = z4, b3 = z4;
        int j = 0;
        for (; j + 4 <= c; j += 4) {
            int4 idx4 = *reinterpret_cast<const int4*>(&s_idx[wv][j]);
            add4(a0, wb1[(size_t)idx4.x * O1Q]);
            add4(a1, wb1[(size_t)idx4.y * O1Q]);
            add4(a2, wb1[(size_t)idx4.z * O1Q]);
            add4(a3, wb1[(size_t)idx4.w * O1Q]);
            if (two) {
                add4(b0, wb2[(size_t)idx4.x * O1Q]);
                add4(b1, wb2[(size_t)idx4.y * O1Q]);
                add4(b2, wb2[(size_t)idx4.z * O1Q]);
                add4(b3, wb2[(size_t)idx4.w * O1Q]);
            }
        }
        for (; j < c; j++) {
            int idx = s_idx[wv][j];
            add4(a0, wb1[(size_t)idx * O1Q]);
            if (two) add4(b0, wb2[(size_t)idx * O1Q]);
        }
        add4(a0, a1); add4(a2, a3); add4(a0, a2);
        float4* dst = &partial4[((size_t)(nt0 + wv) * NCH_I + chunk) * O1Q];
        nt_store4(dst + l, a0);
        if (two) {
            add4(b0, b1); add4(b2, b3); add4(b0, b2);
            nt_store4(dst + 64 + l, b0);
        }
    }
}

// ---- linear reduce: up1[n][t][o] = sum_c partial[nt][c][o], both coalesced -
__global__ void reduce_k(const float* __restrict__ partial, float* __restrict__ up1) {
    int id = blockIdx.x * 256 + threadIdx.x;
    if (id >= NT * O1P) return;
    int nt = id / O1P;
    int o  = id - nt * O1P;
    const float* p = partial + (size_t)nt * NCH_I * O1P + o;
    float s = 0.0f;
#pragma unroll
    for (int c = 0; c < NCH_I; c++) s += __builtin_nontemporal_load(p + c * O1P);
    up1[id] = s;   // up1[n][t][o] == linear id: fully coalesced
}

// ---- fused causal FIR (100-tap) + threshold/refractory scan ----------------
// input up[(n*T + t)*OP + o] (t-major, L2-resident); output s[n][o][t] rows.
__global__ __launch_bounds__(256) void psp_spike_k(const float* __restrict__ up,
                                                   float* __restrict__ s,
                                                   int OP, int O) {
    __shared__ float zrow[16 * PSTRIDE];
    __shared__ float urow[16 * PSTRIDE];
    __shared__ float kern[104];
    int o0  = blockIdx.x * 16;
    int n   = blockIdx.y;
    int tid = threadIdx.x;

    if (tid < 104) {
        float a = (float)tid / 10.0f;
        kern[tid] = (tid < KLEN) ? a * expf(1.0f - a) : 0.0f;
    }
    for (int idx = tid; idx < 16 * T_DIM; idx += 256) {
        int t = idx >> 4, o = idx & 15;
        zrow[o * PSTRIDE + t] = up[((size_t)(n * T_DIM + t)) * OP + o0 + o];
    }
    __syncthreads();
    for (int task = tid; task < 16 * 75; task += 256) {
        int o  = task & 15;
        int t0 = (task >> 4) * 4;
        const float* zr = &zrow[o * PSTRIDE];
        float v0 = zr[t0], v1 = zr[t0 + 1], v2 = zr[t0 + 2], v3 = zr[t0 + 3];
        float a0 = 0.f, a1 = 0.f, a2 = 0.f, a3 = 0.f;
        for (int m = 0; m < KLEN; m++) {
            float km = kern[m];
            a0 += km * v0; a1 += km * v1; a2 += km * v2; a3 += km * v3;
            v3 = v2; v2 = v1; v1 = v0;
            int j = t0 - m - 1;
            v0 = (j >= 0) ? zr[j] : 0.0f;
        }
        *reinterpret_cast<float4*>(&urow[o * PSTRIDE + t0]) = make_float4(a0, a1, a2, a3);
    }
    __syncthreads();
    if (tid < 16) {
        const float A = 0.36787944117144233f;   // exp(-1)
        const float K = -54.365636569180904f;   // -2*10*e
        float p = 0.0f, y = 0.0f;
        float* ur = &urow[tid * PSTRIDE];
        float* sr = &zrow[tid * PSTRIDE];
        for (int t0 = 0; t0 < 296; t0 += 8) {
            float4 ua = *(const float4*)&ur[t0];
            float4 ub = *(const float4*)&ur[t0 + 4];
            float uv[8] = {ua.x, ua.y, ua.z, ua.w, ub.x, ub.y, ub.z, ub.w};
            float sp[8];
#pragma unroll
            for (int q = 0; q < 8; q++) {
                y = A * (y + K * p);
                float v = (uv[q] + y >= 10.0f) ? 1.0f : 0.0f;
                p = A * p + v;
                sp[q] = v;
            }
            *(float4*)&sr[t0]     = make_float4(sp[0], sp[1], sp[2], sp[3]);
            *(float4*)&sr[t0 + 4] = make_float4(sp[4], sp[5], sp[6], sp[7]);
        }
        {
            float4 ua = *(const float4*)&ur[296];
            float uv[4] = {ua.x, ua.y, ua.z, ua.w};
            float sp[4];
#pragma unroll
            for (int q = 0; q < 4; q++) {
                y = A * (y + K * p);
                float v = (uv[q] + y >= 10.0f) ? 1.0f : 0.0f;
                p = A * p + v;
                sp[q] = v;
            }
            *(float4*)&sr[296] = make_float4(sp[0], sp[1], sp[2], sp[3]);
        }
    }
    __syncthreads();
    for (int task = tid; task < 16 * 75; task += 256) {
        int o = task & 15, q = task >> 4;
        int oo = o0 + o;
        if (oo < O) {
            float4 v = *(const float4*)&zrow[o * PSTRIDE + q * 4];
            *reinterpret_cast<float4*>(&s[((size_t)n * O + oo) * T_DIM + q * 4]) = v;
        }
    }
}

// ------- GEMM2: 64-thread blocks (38 CUs of latency chains); w2 in LDS ------
// writes up2[n][t][16] (t-major, padded 16, zero-filled tail)
__global__ __launch_bounds__(64) void gemm2_k(const float* __restrict__ s1,
                                              const float* __restrict__ w2,
                                              float* __restrict__ up2) {
    __shared__ float w2s[O2 * O1];
    int tid = threadIdx.x;
    int nt  = blockIdx.x * 64 + tid;
    for (int q = tid; q < O2 * O1; q += 64) w2s[q] = w2[q];
    __syncthreads();
    if (nt >= NT) return;
    int n = nt / T_DIM, t = nt - n * T_DIM;
    float acc[O2];
#pragma unroll
    for (int k = 0; k < O2; k++) acc[k] = 0.0f;
    const float* sp = s1 + (size_t)n * O1 * T_DIM + t;
    for (int o = 0; o < O1; o++) {
        float v = sp[(size_t)o * T_DIM];
#pragma unroll
        for (int k = 0; k < O2; k++) acc[k] += w2s[k * O1 + o] * v;
    }
    float4* dst = (float4*)&up2[(size_t)nt * 16];
    dst[0] = make_float4(acc[0], acc[1], acc[2], acc[3]);
    dst[1] = make_float4(acc[4], acc[5], acc[6], acc[7]);
    dst[2] = make_float4(acc[8], acc[9], 0.f, 0.f);
    dst[3] = make_float4(0.f, 0.f, 0.f, 0.f);
}

extern "C" void kernel_launch(void* const* d_in, const int* in_sizes, int n_in,
                              void* d_out, int out_size, void* d_ws, size_t ws_size,
                              hipStream_t stream) {
    const float* x  = (const float*)d_in[0];
    const float* w1 = (const float*)d_in[1];
    const float* w2 = (const float*)d_in[2];
    float* out = (float*)d_out;

    char* ws = (char*)d_ws;
    float*        w1t     = (float*)ws;        ws += (size_t)I_DIM * O1P * 4;             // 54.5 MB
    unsigned int* xb      = (unsigned int*)ws; ws += (size_t)N_BATCH * NWORD * T_DIM * 4; // 9.8 MB
    float*        partial = (float*)ws;        ws += (size_t)NT * NCH_I * O1P * 4;        // 63.9 MB
    float*        up1     = (float*)ws;        ws += (size_t)NT * O1P * 4;                // 4.0 MB
    float*        s1      = (float*)ws;        ws += (size_t)N_BATCH * O1 * T_DIM * 4;    // 3.9 MB
    float*        up2     = (float*)ws;                                                   // 154 KB

    prep_k<<<NBM + 512 * 7, 256, 0, stream>>>(x, w1, xb, w1t);
    gather_partial_k<<<2 * NTG * 8, 512, 0, stream>>>((const float4*)w1t, xb,
                                                      (float4*)partial);
    reduce_k<<<(NT * O1P + 255) / 256, 256, 0, stream>>>(partial, up1);
    psp_spike_k<<<dim3((O1 + 15) / 16, N_BATCH), 256, 0, stream>>>(up1, s1, O1P, O1);
    gemm2_k<<<(NT + 63) / 64, 64, 0, stream>>>(s1, w2, up2);
    psp_spike_k<<<dim3(1, N_BATCH), 256, 0, stream>>>(up2, out, 16, O2);
}